// Round 1
// 212.925 us; speedup vs baseline: 1.0112x; 1.0112x over previous
//
#include <hip/hip_runtime.h>

// Problem constants (match reference)
#define B 32
#define S 32
#define N 128
#define U 64
#define E 2
#define NCLS 5

// R8: replace ALL LDS-broadcast (bc buffer) traffic with v_readlane broadcasts.
// The broadcast sources (s, av, hv, rh) live in the broadcasting wave's own
// registers; readlane -> SGPR -> FMA sgpr-operand moves this off the per-CU
// DS pipe (8 waves contending, ~9us/step) onto the per-SIMD VALU pipe (~93%
// idle). bc buffer deleted (LDS 34KB->32KB). A-row bases go through
// readfirstlane so the compiler can emit scalar (s_load) A fetches instead of
// 128 vector global_load_dwordx4 per wave. FMA accumulation order identical
// to R7 (msg edges as two separate u-loops; a-before-h in gates) so the
// output should be bit-identical.
//
// Each block: 8 rows of one batch (4 waves x 2 rows); lane = feature column.

__device__ __forceinline__ float sigmoid_f(float x) {
    return __fdividef(1.f, 1.f + __expf(-x));
}
__device__ __forceinline__ float tanh_f(float x) {
    float t = __expf(-2.f * fabsf(x));
    float y = __fdividef(1.f - t, 1.f + t);
    return copysignf(y, x);
}
// broadcast lane u's value of v to all lanes (VALU pipe, no LDS)
__device__ __forceinline__ float bcast(float v, int u) {
    return __uint_as_float(__builtin_amdgcn_readlane(__float_as_uint(v), u));
}

template <int FIRST, int LAST>
__global__ __launch_bounds__(256) void k_step(
    const float* __restrict__ x, const int* __restrict__ lens,
    const float* __restrict__ hin, float* __restrict__ hout,
    const float* __restrict__ A, const float* __restrict__ Wmsg,
    const float* __restrict__ bmsg, const float* __restrict__ Wg,
    const float* __restrict__ Ug, const float* __restrict__ bg,
    const float* __restrict__ fcw, float* __restrict__ partial, int l) {
    __shared__ float hs[N * U];  // 32 KB: h[b] staged (all rows)
    int tid = threadIdx.x;
    int wave = tid >> 6, lane = tid & 63;
    int b = blockIdx.x >> 4;
    int j = blockIdx.x & 15;
    // wave-uniform row base; readfirstlane makes it provably uniform so the
    // A-row loads below can scalarize (s_load on the SMEM pipe).
    int n0 = __builtin_amdgcn_readfirstlane(j * 8 + wave * 2);

    // ---- stage h[b] (all N rows) into LDS: 2048 float4 over 256 threads
    {
        const float* src;
        if (FIRST) {
            int idx = lens[b] - 1;
            idx = idx < 0 ? 0 : (idx > S - 1 ? S - 1 : idx);
            src = x + (size_t)(b * S + idx) * N * U;
        } else {
            src = hin + (size_t)b * N * U;
        }
        const float4* s4 = (const float4*)src;
        float4* d4 = (float4*)hs;
#pragma unroll
        for (int i = 0; i < 8; i++) d4[tid + i * 256] = s4[tid + i * 256];
    }
    __syncthreads();

    float hv0 = hs[(n0 + 0) * U + lane];
    float hv1 = hs[(n0 + 1) * U + lane];

    // ---- aggregate h: s[row][e] = sum_m A[b,e,row,m] * hs[m][lane]
    float s00 = 0.f, s01 = 0.f, s10 = 0.f, s11 = 0.f;  // [row][e]
    {
        const float4* A00 = (const float4*)(A + (((size_t)b * E + 0) * N + n0 + 0) * N);
        const float4* A10 = (const float4*)(A + (((size_t)b * E + 0) * N + n0 + 1) * N);
        const float4* A01 = (const float4*)(A + (((size_t)b * E + 1) * N + n0 + 0) * N);
        const float4* A11 = (const float4*)(A + (((size_t)b * E + 1) * N + n0 + 1) * N);
#pragma unroll 8
        for (int m4 = 0; m4 < N / 4; ++m4) {
            float4 a00 = A00[m4], a10 = A10[m4], a01 = A01[m4], a11 = A11[m4];
            float q0 = hs[(m4 * 4 + 0) * U + lane];
            float q1 = hs[(m4 * 4 + 1) * U + lane];
            float q2 = hs[(m4 * 4 + 2) * U + lane];
            float q3 = hs[(m4 * 4 + 3) * U + lane];
            s00 = fmaf(a00.x, q0, s00); s00 = fmaf(a00.y, q1, s00);
            s00 = fmaf(a00.z, q2, s00); s00 = fmaf(a00.w, q3, s00);
            s10 = fmaf(a10.x, q0, s10); s10 = fmaf(a10.y, q1, s10);
            s10 = fmaf(a10.z, q2, s10); s10 = fmaf(a10.w, q3, s10);
            s01 = fmaf(a01.x, q0, s01); s01 = fmaf(a01.y, q1, s01);
            s01 = fmaf(a01.z, q2, s01); s01 = fmaf(a01.w, q3, s01);
            s11 = fmaf(a11.x, q0, s11); s11 = fmaf(a11.y, q1, s11);
            s11 = fmaf(a11.z, q2, s11); s11 = fmaf(a11.w, q3, s11);
        }
    }

    // ---- a[row] = sum_e s[row][e] @ Wmsg[l][e] + bmsg[l]  (readlane bcast)
    // Two separate edge loops keep R7's exact accumulation order.
    float bm = bmsg[l * U + lane];
    float av0 = bm, av1 = bm;
    {
        const float* W0 = Wmsg + (size_t)(l * E + 0) * U * U + lane;
        const float* W1 = W0 + U * U;
#pragma unroll 16
        for (int u = 0; u < U; ++u) {
            float w = W0[u * U];
            av0 = fmaf(bcast(s00, u), w, av0);
            av1 = fmaf(bcast(s10, u), w, av1);
        }
#pragma unroll 16
        for (int u = 0; u < U; ++u) {
            float w = W1[u * U];
            av0 = fmaf(bcast(s01, u), w, av0);
            av1 = fmaf(bcast(s11, u), w, av1);
        }
    }

    // ---- gate matmuls (lane = output column v); a,h broadcast via readlane
    const float* Wg0 = Wg + (size_t)l * 3 * U * U + lane;
    const float* Wg1 = Wg0 + U * U;
    const float* Wg2 = Wg1 + U * U;
    const float* Ug0 = Ug + (size_t)l * 3 * U * U + lane;
    const float* Ug1 = Ug0 + U * U;
    const float* Ug2 = Ug1 + U * U;
    float accz0 = bg[(l * 3 + 0) * U + lane], accz1 = accz0;
    float accr0 = bg[(l * 3 + 1) * U + lane], accr1 = accr0;
    float accc0 = bg[(l * 3 + 2) * U + lane], accc1 = accc0;
#pragma unroll 16
    for (int u = 0; u < U; ++u) {
        float w0 = Wg0[u * U], w1 = Wg1[u * U], w2 = Wg2[u * U];
        float g0 = Ug0[u * U], g1 = Ug1[u * U];
        float a0 = bcast(av0, u), a1 = bcast(av1, u);
        float h0 = bcast(hv0, u), h1 = bcast(hv1, u);
        accz0 = fmaf(a0, w0, accz0); accz0 = fmaf(h0, g0, accz0);
        accz1 = fmaf(a1, w0, accz1); accz1 = fmaf(h1, g0, accz1);
        accr0 = fmaf(a0, w1, accr0); accr0 = fmaf(h0, g1, accr0);
        accr1 = fmaf(a1, w1, accr1); accr1 = fmaf(h1, g1, accr1);
        accc0 = fmaf(a0, w2, accc0);
        accc1 = fmaf(a1, w2, accc1);
    }
    float rg0 = sigmoid_f(accr0), rg1 = sigmoid_f(accr1);
    float rh0 = rg0 * hv0, rh1 = rg1 * hv1;
#pragma unroll 16
    for (int u = 0; u < U; ++u) {
        float g2 = Ug2[u * U];
        accc0 = fmaf(bcast(rh0, u), g2, accc0);
        accc1 = fmaf(bcast(rh1, u), g2, accc1);
    }
    float zg0 = sigmoid_f(accz0), zg1 = sigmoid_f(accz1);
    float hn0 = (1.f - zg0) * hv0 + zg0 * tanh_f(accc0);
    float hn1 = (1.f - zg1) * hv1 + zg1 * tanh_f(accc1);

    if (!LAST) {
        hout[((size_t)b * N + n0 + 0) * U + lane] = hn0;
        hout[((size_t)b * N + n0 + 1) * U + lane] = hn1;
    } else {
        // fused classification partial: max over our 8 rows of relu(h')@fc_w
        float lg0[NCLS], lg1[NCLS];
        float rv0 = hn0 > 0.f ? hn0 : 0.f;
        float rv1 = hn1 > 0.f ? hn1 : 0.f;
#pragma unroll
        for (int c = 0; c < NCLS; c++) {
            float w = fcw[lane * NCLS + c];
            lg0[c] = rv0 * w;
            lg1[c] = rv1 * w;
        }
#pragma unroll
        for (int off = 32; off; off >>= 1) {
#pragma unroll
            for (int c = 0; c < NCLS; c++) {
                lg0[c] += __shfl_xor(lg0[c], off, 64);
                lg1[c] += __shfl_xor(lg1[c], off, 64);
            }
        }
        __syncthreads();  // all waves done with hs; reuse hs as reduce buffer
        if (lane == 0) {
#pragma unroll
            for (int c = 0; c < NCLS; c++) hs[wave * NCLS + c] = fmaxf(lg0[c], lg1[c]);
        }
        __syncthreads();
        if (tid < NCLS) {
            float m = hs[tid];
            for (int w = 1; w < 4; ++w) m = fmaxf(m, hs[w * NCLS + tid]);
            partial[(size_t)(b * 16 + j) * NCLS + tid] = m;
        }
    }
}

// ---------------------------------------------------------------------------
// k_final: out[b][c] = max over 16 block-partials + fc_b
__global__ void k_final(const float* __restrict__ partial, const float* __restrict__ fcb,
                        float* __restrict__ out) {
    int b = blockIdx.x, c = threadIdx.x;
    if (c < NCLS) {
        float m = -3.4e38f;
        for (int jj = 0; jj < 16; ++jj)
            m = fmaxf(m, partial[(size_t)(b * 16 + jj) * NCLS + c]);
        out[b * NCLS + c] = m + fcb[c];
    }
}

// ---------------------------------------------------------------------------
extern "C" void kernel_launch(void* const* d_in, const int* in_sizes, int n_in,
                              void* d_out, int out_size, void* d_ws, size_t ws_size,
                              hipStream_t stream) {
    const float* x    = (const float*)d_in[0];
    const int*   lens = (const int*)d_in[1];
    const float* A    = (const float*)d_in[2];
    const float* Wmsg = (const float*)d_in[3];
    const float* bmsg = (const float*)d_in[4];
    const float* Wg   = (const float*)d_in[5];
    const float* Ug   = (const float*)d_in[6];
    const float* bg   = (const float*)d_in[7];
    const float* fcw  = (const float*)d_in[8];
    const float* fcb  = (const float*)d_in[9];
    float* out = (float*)d_out;

    float* hA      = (float*)d_ws;                   // [B][N][U]
    float* hB      = hA + (size_t)B * N * U;         // [B][N][U]
    float* partial = hB + (size_t)B * N * U;         // [B][16][NCLS]

    // steps 0-2: layer 0; steps 3-5: layer 1
    k_step<1, 0><<<B * 16, 256, 0, stream>>>(x, lens, nullptr, hA, A, Wmsg, bmsg, Wg, Ug, bg, fcw, partial, 0);
    k_step<0, 0><<<B * 16, 256, 0, stream>>>(x, lens, hA, hB, A, Wmsg, bmsg, Wg, Ug, bg, fcw, partial, 0);
    k_step<0, 0><<<B * 16, 256, 0, stream>>>(x, lens, hB, hA, A, Wmsg, bmsg, Wg, Ug, bg, fcw, partial, 0);
    k_step<0, 0><<<B * 16, 256, 0, stream>>>(x, lens, hA, hB, A, Wmsg, bmsg, Wg, Ug, bg, fcw, partial, 1);
    k_step<0, 0><<<B * 16, 256, 0, stream>>>(x, lens, hB, hA, A, Wmsg, bmsg, Wg, Ug, bg, fcw, partial, 1);
    k_step<0, 1><<<B * 16, 256, 0, stream>>>(x, lens, hA, hB, A, Wmsg, bmsg, Wg, Ug, bg, fcw, partial, 1);
    k_final<<<B, 64, 0, stream>>>(partial, fcb, out);
}

// Round 2
// 209.241 us; speedup vs baseline: 1.0290x; 1.0176x over previous
//
#include <hip/hip_runtime.h>

// Problem constants (match reference)
#define B 32
#define S 32
#define N 128
#define U 64
#define E 2
#define NCLS 5

// R9: barrier-free k_step. R8 (readlane broadcasts) was neutral -> DS pipe was
// not the limiter. New theory: the stage->__syncthreads() phase-locks all 8
// resident waves per CU, so the stage/aggregate/weight-stream/VALU phases run
// SERIALLY at each phase's own bottleneck (sum ~20us) instead of overlapping.
// Fix: drop LDS h-staging entirely; the aggregate reads h[m][lane] directly
// from global (fully coalesced 256B/wave-load; h[b]=32KB is L1-resident and
// shared by all 4 waves of the block). No __syncthreads in the hot path ->
// waves drift out of phase and VMEM/VALU/SMEM pipes overlap across waves.
// Accumulation order identical to R7/R8 -> bit-identical output.
//
// Each block: 8 rows of one batch (4 waves x 2 rows); lane = feature column.

__device__ __forceinline__ float sigmoid_f(float x) {
    return __fdividef(1.f, 1.f + __expf(-x));
}
__device__ __forceinline__ float tanh_f(float x) {
    float t = __expf(-2.f * fabsf(x));
    float y = __fdividef(1.f - t, 1.f + t);
    return copysignf(y, x);
}
// broadcast lane u's value of v to all lanes (VALU pipe, no LDS)
__device__ __forceinline__ float bcast(float v, int u) {
    return __uint_as_float(__builtin_amdgcn_readlane(__float_as_uint(v), u));
}

template <int FIRST, int LAST>
__global__ __launch_bounds__(256) void k_step(
    const float* __restrict__ x, const int* __restrict__ lens,
    const float* __restrict__ hin, float* __restrict__ hout,
    const float* __restrict__ A, const float* __restrict__ Wmsg,
    const float* __restrict__ bmsg, const float* __restrict__ Wg,
    const float* __restrict__ Ug, const float* __restrict__ bg,
    const float* __restrict__ fcw, float* __restrict__ partial, int l) {
    __shared__ float red[4 * NCLS];  // only used in LAST tail reduce (80 B)
    int tid = threadIdx.x;
    int wave = tid >> 6, lane = tid & 63;
    int b = blockIdx.x >> 4;
    int j = blockIdx.x & 15;
    // wave-uniform row base; readfirstlane keeps A-row addresses scalar-provable
    int n0 = __builtin_amdgcn_readfirstlane(j * 8 + wave * 2);

    // h source: global, no staging. h[b] = 32KB, L1-resident, shared by the
    // block's 4 waves (same addresses -> L1 hits after first touch).
    const float* __restrict__ hsrc;
    if (FIRST) {
        int idx = lens[b] - 1;
        idx = idx < 0 ? 0 : (idx > S - 1 ? S - 1 : idx);
        hsrc = x + (size_t)(b * S + idx) * N * U;
    } else {
        hsrc = hin + (size_t)b * N * U;
    }

    float hv0 = hsrc[(n0 + 0) * U + lane];
    float hv1 = hsrc[(n0 + 1) * U + lane];

    // ---- aggregate h: s[row][e] = sum_m A[b,e,row,m] * h[m][lane]
    float s00 = 0.f, s01 = 0.f, s10 = 0.f, s11 = 0.f;  // [row][e]
    {
        const float4* A00 = (const float4*)(A + (((size_t)b * E + 0) * N + n0 + 0) * N);
        const float4* A10 = (const float4*)(A + (((size_t)b * E + 0) * N + n0 + 1) * N);
        const float4* A01 = (const float4*)(A + (((size_t)b * E + 1) * N + n0 + 0) * N);
        const float4* A11 = (const float4*)(A + (((size_t)b * E + 1) * N + n0 + 1) * N);
#pragma unroll 8
        for (int m4 = 0; m4 < N / 4; ++m4) {
            float4 a00 = A00[m4], a10 = A10[m4], a01 = A01[m4], a11 = A11[m4];
            float q0 = hsrc[(m4 * 4 + 0) * U + lane];
            float q1 = hsrc[(m4 * 4 + 1) * U + lane];
            float q2 = hsrc[(m4 * 4 + 2) * U + lane];
            float q3 = hsrc[(m4 * 4 + 3) * U + lane];
            s00 = fmaf(a00.x, q0, s00); s00 = fmaf(a00.y, q1, s00);
            s00 = fmaf(a00.z, q2, s00); s00 = fmaf(a00.w, q3, s00);
            s10 = fmaf(a10.x, q0, s10); s10 = fmaf(a10.y, q1, s10);
            s10 = fmaf(a10.z, q2, s10); s10 = fmaf(a10.w, q3, s10);
            s01 = fmaf(a01.x, q0, s01); s01 = fmaf(a01.y, q1, s01);
            s01 = fmaf(a01.z, q2, s01); s01 = fmaf(a01.w, q3, s01);
            s11 = fmaf(a11.x, q0, s11); s11 = fmaf(a11.y, q1, s11);
            s11 = fmaf(a11.z, q2, s11); s11 = fmaf(a11.w, q3, s11);
        }
    }

    // ---- a[row] = sum_e s[row][e] @ Wmsg[l][e] + bmsg[l]  (readlane bcast)
    // Two separate edge loops keep the exact accumulation order.
    float bm = bmsg[l * U + lane];
    float av0 = bm, av1 = bm;
    {
        const float* W0 = Wmsg + (size_t)(l * E + 0) * U * U + lane;
        const float* W1 = W0 + U * U;
#pragma unroll 16
        for (int u = 0; u < U; ++u) {
            float w = W0[u * U];
            av0 = fmaf(bcast(s00, u), w, av0);
            av1 = fmaf(bcast(s10, u), w, av1);
        }
#pragma unroll 16
        for (int u = 0; u < U; ++u) {
            float w = W1[u * U];
            av0 = fmaf(bcast(s01, u), w, av0);
            av1 = fmaf(bcast(s11, u), w, av1);
        }
    }

    // ---- gate matmuls (lane = output column v); a,h broadcast via readlane
    const float* Wg0 = Wg + (size_t)l * 3 * U * U + lane;
    const float* Wg1 = Wg0 + U * U;
    const float* Wg2 = Wg1 + U * U;
    const float* Ug0 = Ug + (size_t)l * 3 * U * U + lane;
    const float* Ug1 = Ug0 + U * U;
    const float* Ug2 = Ug1 + U * U;
    float accz0 = bg[(l * 3 + 0) * U + lane], accz1 = accz0;
    float accr0 = bg[(l * 3 + 1) * U + lane], accr1 = accr0;
    float accc0 = bg[(l * 3 + 2) * U + lane], accc1 = accc0;
#pragma unroll 16
    for (int u = 0; u < U; ++u) {
        float w0 = Wg0[u * U], w1 = Wg1[u * U], w2 = Wg2[u * U];
        float g0 = Ug0[u * U], g1 = Ug1[u * U];
        float a0 = bcast(av0, u), a1 = bcast(av1, u);
        float h0 = bcast(hv0, u), h1 = bcast(hv1, u);
        accz0 = fmaf(a0, w0, accz0); accz0 = fmaf(h0, g0, accz0);
        accz1 = fmaf(a1, w0, accz1); accz1 = fmaf(h1, g0, accz1);
        accr0 = fmaf(a0, w1, accr0); accr0 = fmaf(h0, g1, accr0);
        accr1 = fmaf(a1, w1, accr1); accr1 = fmaf(h1, g1, accr1);
        accc0 = fmaf(a0, w2, accc0);
        accc1 = fmaf(a1, w2, accc1);
    }
    float rg0 = sigmoid_f(accr0), rg1 = sigmoid_f(accr1);
    float rh0 = rg0 * hv0, rh1 = rg1 * hv1;
#pragma unroll 16
    for (int u = 0; u < U; ++u) {
        float g2 = Ug2[u * U];
        accc0 = fmaf(bcast(rh0, u), g2, accc0);
        accc1 = fmaf(bcast(rh1, u), g2, accc1);
    }
    float zg0 = sigmoid_f(accz0), zg1 = sigmoid_f(accz1);
    float hn0 = (1.f - zg0) * hv0 + zg0 * tanh_f(accc0);
    float hn1 = (1.f - zg1) * hv1 + zg1 * tanh_f(accc1);

    if (!LAST) {
        hout[((size_t)b * N + n0 + 0) * U + lane] = hn0;
        hout[((size_t)b * N + n0 + 1) * U + lane] = hn1;
    } else {
        // fused classification partial: max over our 8 rows of relu(h')@fc_w
        float lg0[NCLS], lg1[NCLS];
        float rv0 = hn0 > 0.f ? hn0 : 0.f;
        float rv1 = hn1 > 0.f ? hn1 : 0.f;
#pragma unroll
        for (int c = 0; c < NCLS; c++) {
            float w = fcw[lane * NCLS + c];
            lg0[c] = rv0 * w;
            lg1[c] = rv1 * w;
        }
#pragma unroll
        for (int off = 32; off; off >>= 1) {
#pragma unroll
            for (int c = 0; c < NCLS; c++) {
                lg0[c] += __shfl_xor(lg0[c], off, 64);
                lg1[c] += __shfl_xor(lg1[c], off, 64);
            }
        }
        if (lane == 0) {
#pragma unroll
            for (int c = 0; c < NCLS; c++) red[wave * NCLS + c] = fmaxf(lg0[c], lg1[c]);
        }
        __syncthreads();  // only barrier in the kernel: cross-wave max reduce
        if (tid < NCLS) {
            float m = red[tid];
            for (int w = 1; w < 4; ++w) m = fmaxf(m, red[w * NCLS + tid]);
            partial[(size_t)(b * 16 + j) * NCLS + tid] = m;
        }
    }
}

// ---------------------------------------------------------------------------
// k_final: out[b][c] = max over 16 block-partials + fc_b
__global__ void k_final(const float* __restrict__ partial, const float* __restrict__ fcb,
                        float* __restrict__ out) {
    int b = blockIdx.x, c = threadIdx.x;
    if (c < NCLS) {
        float m = -3.4e38f;
        for (int jj = 0; jj < 16; ++jj)
            m = fmaxf(m, partial[(size_t)(b * 16 + jj) * NCLS + c]);
        out[b * NCLS + c] = m + fcb[c];
    }
}

// ---------------------------------------------------------------------------
extern "C" void kernel_launch(void* const* d_in, const int* in_sizes, int n_in,
                              void* d_out, int out_size, void* d_ws, size_t ws_size,
                              hipStream_t stream) {
    const float* x    = (const float*)d_in[0];
    const int*   lens = (const int*)d_in[1];
    const float* A    = (const float*)d_in[2];
    const float* Wmsg = (const float*)d_in[3];
    const float* bmsg = (const float*)d_in[4];
    const float* Wg   = (const float*)d_in[5];
    const float* Ug   = (const float*)d_in[6];
    const float* bg   = (const float*)d_in[7];
    const float* fcw  = (const float*)d_in[8];
    const float* fcb  = (const float*)d_in[9];
    float* out = (float*)d_out;

    float* hA      = (float*)d_ws;                   // [B][N][U]
    float* hB      = hA + (size_t)B * N * U;         // [B][N][U]
    float* partial = hB + (size_t)B * N * U;         // [B][16][NCLS]

    // steps 0-2: layer 0; steps 3-5: layer 1
    k_step<1, 0><<<B * 16, 256, 0, stream>>>(x, lens, nullptr, hA, A, Wmsg, bmsg, Wg, Ug, bg, fcw, partial, 0);
    k_step<0, 0><<<B * 16, 256, 0, stream>>>(x, lens, hA, hB, A, Wmsg, bmsg, Wg, Ug, bg, fcw, partial, 0);
    k_step<0, 0><<<B * 16, 256, 0, stream>>>(x, lens, hB, hA, A, Wmsg, bmsg, Wg, Ug, bg, fcw, partial, 0);
    k_step<0, 0><<<B * 16, 256, 0, stream>>>(x, lens, hA, hB, A, Wmsg, bmsg, Wg, Ug, bg, fcw, partial, 1);
    k_step<0, 0><<<B * 16, 256, 0, stream>>>(x, lens, hB, hA, A, Wmsg, bmsg, Wg, Ug, bg, fcw, partial, 1);
    k_step<0, 1><<<B * 16, 256, 0, stream>>>(x, lens, hA, hB, A, Wmsg, bmsg, Wg, Ug, bg, fcw, partial, 1);
    k_final<<<B, 64, 0, stream>>>(partial, fcb, out);
}